// Round 3
// baseline (1979.937 us; speedup 1.0000x reference)
//
#include <hip/hip_runtime.h>
#include <hip/hip_bf16.h>

#define D_MODEL 1024
#define HEADS   16
#define DKH     64
#define BATCH   2
#define SEQ     2048
#define NTOK    (BATCH*SEQ)   // 4096

using bf16 = __hip_bfloat16;

__device__ __forceinline__ float cvt(float x){ return x; }
__device__ __forceinline__ float cvt(bf16 x){ return __bfloat162float(x); }
__device__ __forceinline__ void stv(float* p, float v){ *p = v; }
__device__ __forceinline__ void stv(bf16* p, float v){ *p = __float2bfloat16(v); }

// ---------------------------------------------------------------------------
// C[m,n] = sum_k A[m,k] * W[k,n] + bias[n]     (W, bias are fp32 inputs)
// 64x64 tile, BK=16, 256 threads, 4x4 microtile per thread. fp32 accumulate.
// ---------------------------------------------------------------------------
template<typename TA, typename TC>
__global__ __launch_bounds__(256)
void gemm_bias(const TA* __restrict__ A, const float* __restrict__ W,
               const float* __restrict__ bias, TC* __restrict__ C,
               int M, int N, int K)
{
  __shared__ float As[16][65];   // As[k][m]
  __shared__ float Bs[16][65];   // Bs[k][n]
  const int bm = blockIdx.y * 64, bn = blockIdx.x * 64;
  const int tid = threadIdx.x;
  const int tx = tid & 15, ty = tid >> 4;
  float acc[4][4] = {};
  for (int k0 = 0; k0 < K; k0 += 16) {
    {
      const int r = tid >> 2, cb = (tid & 3) * 4;       // A: 64 rows x 16 k
      #pragma unroll
      for (int v = 0; v < 4; ++v)
        As[cb + v][r] = cvt(A[(size_t)(bm + r) * K + k0 + cb + v]);
      const int kk = tid >> 4, nb = (tid & 15) * 4;     // W: 16 k x 64 n
      #pragma unroll
      for (int v = 0; v < 4; ++v)
        Bs[kk][nb + v] = W[(size_t)(k0 + kk) * N + bn + nb + v];
    }
    __syncthreads();
    #pragma unroll
    for (int kk = 0; kk < 16; ++kk) {
      float a[4], b[4];
      #pragma unroll
      for (int u = 0; u < 4; ++u) a[u] = As[kk][ty * 4 + u];
      #pragma unroll
      for (int u = 0; u < 4; ++u) b[u] = Bs[kk][tx * 4 + u];
      #pragma unroll
      for (int um = 0; um < 4; ++um)
        #pragma unroll
        for (int un = 0; un < 4; ++un)
          acc[um][un] = fmaf(a[um], b[un], acc[um][un]);
    }
    __syncthreads();
  }
  #pragma unroll
  for (int um = 0; um < 4; ++um) {
    const int m = bm + ty * 4 + um;
    #pragma unroll
    for (int un = 0; un < 4; ++un) {
      const int n = bn + tx * 4 + un;
      stv(&C[(size_t)m * N + n], acc[um][un] + bias[n]);
    }
  }
}

// ---------------------------------------------------------------------------
// Softmax-over-i stats: for each (b,h,j): m_j = max_i s_ij, l_j = sum_i e^{s-m}
// Block = one (b,h, 64-wide j tile); online scan over all i tiles.
// ---------------------------------------------------------------------------
__global__ __launch_bounds__(256)
void attn_stats(const bf16* __restrict__ Qp, const bf16* __restrict__ Kp,
                float* __restrict__ Mj, float* __restrict__ Lj)
{
  const int jt = blockIdx.x;          // SEQ/64 tiles
  const int bh = blockIdx.y;          // B*HEADS
  const int b = bh >> 4, h = bh & 15;
  const int j0 = jt * 64;
  const int tid = threadIdx.x;
  const int tx = tid & 15, ty = tid >> 4;
  __shared__ float Ks[64][65], Qs[64][65], Sc[64][65];
  __shared__ float pm[4][64], ps[4][64];
  __shared__ float mrun[64], lrun[64];
  if (tid < 64) { mrun[tid] = -1e30f; lrun[tid] = 0.f; }
  for (int e = tid; e < 64 * 64; e += 256) {
    const int r = e >> 6, d = e & 63;
    Ks[r][d] = cvt(Kp[(size_t)(b * SEQ + j0 + r) * D_MODEL + h * DKH + d]);
  }
  for (int it = 0; it < SEQ / 64; ++it) {
    const int i0 = it * 64;
    __syncthreads();
    for (int e = tid; e < 64 * 64; e += 256) {
      const int r = e >> 6, d = e & 63;
      Qs[r][d] = cvt(Qp[(size_t)(b * SEQ + i0 + r) * D_MODEL + h * DKH + d]);
    }
    __syncthreads();
    float s[4][4] = {};
    for (int d = 0; d < 64; ++d) {
      float a[4], bb[4];
      #pragma unroll
      for (int u = 0; u < 4; ++u) a[u]  = Qs[ty * 4 + u][d];
      #pragma unroll
      for (int u = 0; u < 4; ++u) bb[u] = Ks[tx * 4 + u][d];
      #pragma unroll
      for (int um = 0; um < 4; ++um)
        #pragma unroll
        for (int un = 0; un < 4; ++un)
          s[um][un] = fmaf(a[um], bb[un], s[um][un]);
    }
    #pragma unroll
    for (int um = 0; um < 4; ++um)
      #pragma unroll
      for (int un = 0; un < 4; ++un)
        Sc[ty * 4 + um][tx * 4 + un] = s[um][un] * 0.125f;
    __syncthreads();
    {  // partial max/sumexp over 16 i's each; 4 segments per column j
      const int j = tid & 63, seg = tid >> 6;
      float tm = -1e30f;
      for (int q = 0; q < 16; ++q) tm = fmaxf(tm, Sc[seg * 16 + q][j]);
      float tsum = 0.f;
      for (int q = 0; q < 16; ++q) tsum += __expf(Sc[seg * 16 + q][j] - tm);
      pm[seg][j] = tm; ps[seg][j] = tsum;
    }
    __syncthreads();
    if (tid < 64) {  // merge 4 partials, then online-merge into running stats
      const float m4 = fmaxf(fmaxf(pm[0][tid], pm[1][tid]),
                             fmaxf(pm[2][tid], pm[3][tid]));
      const float s4 = ps[0][tid] * __expf(pm[0][tid] - m4)
                     + ps[1][tid] * __expf(pm[1][tid] - m4)
                     + ps[2][tid] * __expf(pm[2][tid] - m4)
                     + ps[3][tid] * __expf(pm[3][tid] - m4);
      const float mo = mrun[tid];
      const float mn = fmaxf(mo, m4);
      lrun[tid] = lrun[tid] * __expf(mo - mn) + s4 * __expf(m4 - mn);
      mrun[tid] = mn;
    }
  }
  __syncthreads();
  if (tid < 64) {
    Mj[(size_t)bh * SEQ + j0 + tid] = mrun[tid];
    Lj[(size_t)bh * SEQ + j0 + tid] = lrun[tid];
  }
}

// ---------------------------------------------------------------------------
// PV pass: X[b,i,h,:] = sum_j exp(s_ij - m_j)/l_j * V[b,j,h,:]
// Block = one (b,h, 64-wide i tile); loops over j tiles; stats precomputed.
// ---------------------------------------------------------------------------
__global__ __launch_bounds__(256)
void attn_pv(const bf16* __restrict__ Qp, const bf16* __restrict__ Kp,
             const bf16* __restrict__ Vp, const float* __restrict__ Mj,
             const float* __restrict__ Lj, bf16* __restrict__ X)
{
  const int it = blockIdx.x;
  const int bh = blockIdx.y;
  const int b = bh >> 4, h = bh & 15;
  const int i0 = it * 64;
  const int tid = threadIdx.x;
  const int tx = tid & 15, ty = tid >> 4;
  __shared__ float Qs[64][65], Ks[64][65], Vs[64][65], Pt[64][65];
  __shared__ float mjs[64], lji[64];
  for (int e = tid; e < 64 * 64; e += 256) {
    const int r = e >> 6, d = e & 63;
    Qs[r][d] = cvt(Qp[(size_t)(b * SEQ + i0 + r) * D_MODEL + h * DKH + d]);
  }
  float acc[4][4] = {};
  for (int jt = 0; jt < SEQ / 64; ++jt) {
    const int j0 = jt * 64;
    __syncthreads();
    for (int e = tid; e < 64 * 64; e += 256) {
      const int r = e >> 6, d = e & 63;
      const size_t base = (size_t)(b * SEQ + j0 + r) * D_MODEL + h * DKH + d;
      Ks[r][d] = cvt(Kp[base]);
      Vs[r][d] = cvt(Vp[base]);
    }
    if (tid < 64) {
      mjs[tid] = Mj[(size_t)bh * SEQ + j0 + tid];
      lji[tid] = 1.f / fmaxf(Lj[(size_t)bh * SEQ + j0 + tid], 1e-20f);
    }
    __syncthreads();
    float s[4][4] = {};
    for (int d = 0; d < 64; ++d) {
      float a[4], bb[4];
      #pragma unroll
      for (int u = 0; u < 4; ++u) a[u]  = Qs[ty * 4 + u][d];
      #pragma unroll
      for (int u = 0; u < 4; ++u) bb[u] = Ks[tx * 4 + u][d];
      #pragma unroll
      for (int um = 0; um < 4; ++um)
        #pragma unroll
        for (int un = 0; un < 4; ++un)
          s[um][un] = fmaf(a[um], bb[un], s[um][un]);
    }
    #pragma unroll
    for (int um = 0; um < 4; ++um)
      #pragma unroll
      for (int un = 0; un < 4; ++un) {
        const int j = tx * 4 + un;
        Pt[ty * 4 + um][j] = __expf(s[um][un] * 0.125f - mjs[j]) * lji[j];
      }
    __syncthreads();
    for (int j = 0; j < 64; ++j) {
      float a[4], bb[4];
      #pragma unroll
      for (int u = 0; u < 4; ++u) a[u]  = Pt[ty * 4 + u][j];
      #pragma unroll
      for (int u = 0; u < 4; ++u) bb[u] = Vs[j][tx * 4 + u];
      #pragma unroll
      for (int um = 0; um < 4; ++um)
        #pragma unroll
        for (int un = 0; un < 4; ++un)
          acc[um][un] = fmaf(a[um], bb[un], acc[um][un]);
    }
  }
  #pragma unroll
  for (int um = 0; um < 4; ++um)
    #pragma unroll
    for (int un = 0; un < 4; ++un)
      stv(&X[(size_t)(b * SEQ + i0 + ty * 4 + um) * D_MODEL + h * DKH + tx * 4 + un],
          acc[um][un]);
}

// ---------------------------------------------------------------------------
extern "C" void kernel_launch(void* const* d_in, const int* in_sizes, int n_in,
                              void* d_out, int out_size, void* d_ws, size_t ws_size,
                              hipStream_t stream)
{
  // Reference dtypes are float32 for ALL inputs and the output.
  const float* q  = (const float*)d_in[0];
  const float* k  = (const float*)d_in[1];
  const float* v  = (const float*)d_in[2];
  const float* Wq = (const float*)d_in[3];
  const float* bq = (const float*)d_in[4];
  const float* Wk = (const float*)d_in[5];
  const float* bk = (const float*)d_in[6];
  const float* Wv = (const float*)d_in[7];
  const float* bv = (const float*)d_in[8];
  const float* Wo = (const float*)d_in[9];
  const float* bo = (const float*)d_in[10];
  float* out = (float*)d_out;

  // ws layout: small stats arrays FIRST, then bf16 staging buffers.
  //   Mj, Lj : fp32, 256 KiB each
  //   Qb, Kb, Vb, Xb : bf16, 8 MiB each
  // Total ~32.5 MiB.
  char* ws = (char*)d_ws;
  const size_t STATB = (size_t)BATCH * HEADS * SEQ * sizeof(float);      // 256 KiB
  const size_t TOKB  = (size_t)NTOK * D_MODEL * sizeof(bf16);            // 8 MiB
  float* Mj = (float*)(ws);
  float* Lj = (float*)(ws + STATB);
  bf16*  Qb = (bf16*)(ws + 2 * STATB);
  bf16*  Kb = (bf16*)(ws + 2 * STATB + TOKB);
  bf16*  Vb = (bf16*)(ws + 2 * STATB + 2 * TOKB);
  bf16*  Xb = (bf16*)(ws + 2 * STATB + 3 * TOKB);

  dim3 blk(256);
  dim3 gproj(D_MODEL / 64, NTOK / 64);   // (16, 64)
  gemm_bias<float, bf16><<<gproj, blk, 0, stream>>>(q, Wq, bq, Qb, NTOK, D_MODEL, D_MODEL);
  gemm_bias<float, bf16><<<gproj, blk, 0, stream>>>(k, Wk, bk, Kb, NTOK, D_MODEL, D_MODEL);
  gemm_bias<float, bf16><<<gproj, blk, 0, stream>>>(v, Wv, bv, Vb, NTOK, D_MODEL, D_MODEL);

  dim3 gattn(SEQ / 64, BATCH * HEADS);   // (32, 32)
  attn_stats<<<gattn, blk, 0, stream>>>(Qb, Kb, Mj, Lj);
  attn_pv<<<gattn, blk, 0, stream>>>(Qb, Kb, Vb, Mj, Lj, Xb);

  gemm_bias<bf16, float><<<gproj, blk, 0, stream>>>(Xb, Wo, bo, out, NTOK, D_MODEL, D_MODEL);
}

// Round 4
// 418.697 us; speedup vs baseline: 4.7288x; 4.7288x over previous
//
#include <hip/hip_runtime.h>
#include <hip/hip_bf16.h>

#define SEQ   2048
#define NH    16
#define DK    64
#define DM    1024
#define NTOK  4096

typedef unsigned short u16;
typedef unsigned int   u32;
typedef short bhalf8 __attribute__((ext_vector_type(8)));   // 8 bf16 = 4 VGPRs
typedef float floatx4 __attribute__((ext_vector_type(4)));  // MFMA acc

#define MFMA16(a,b,c) __builtin_amdgcn_mfma_f32_16x16x32_bf16(a,b,c,0,0,0)

// fp32 -> bf16 round-to-nearest-even
__device__ __forceinline__ u16 f2b(float f){
  union { float f; u32 u; } v; v.f = f;
  u32 r = v.u + 0x7fffu + ((v.u >> 16) & 1u);
  return (u16)(r >> 16);
}
__device__ __forceinline__ u32 pack2(float a, float b){
  return (u32)f2b(a) | ((u32)f2b(b) << 16);
}

// ---------------------------------------------------------------------------
// Transpose + convert: W fp32 [k][n] (1024x1024) -> Wt bf16 [n][k]
// ---------------------------------------------------------------------------
__global__ __launch_bounds__(256)
void wtrans(const float* __restrict__ W, u16* __restrict__ Wt)
{
  __shared__ __align__(16) u16 T[64][68];
  const int k0 = blockIdx.y * 64, n0 = blockIdx.x * 64;
  const int t = threadIdx.x;
  #pragma unroll
  for (int p = 0; p < 16; ++p){
    int e = p*256 + t, k = e >> 6, n = e & 63;
    T[n][k] = f2b(W[(size_t)(k0+k)*DM + n0 + n]);
  }
  __syncthreads();
  #pragma unroll
  for (int p = 0; p < 8; ++p){
    int e = p*256 + t, n = e >> 5, kp = e & 31;
    u32 val = *(const u32*)&T[n][2*kp];
    *(u32*)&Wt[(size_t)(n0+n)*DM + k0 + 2*kp] = val;
  }
}

// ---------------------------------------------------------------------------
// MFMA GEMM: C[m][n] = sum_k A[m][k] * Wt[n][k] + bias[n]
// M=4096, N=1024, K=1024. 128x128 tile, BK=32, 256 thr (4 waves, 2x2 of 64x64).
// ABF16: A is bf16 (else fp32, converted while staging).
// OMODE: 0 = bf16 C[m][DM]; 1 = bf16 Vt[((b*16+h)*64+d)*SEQ + s]; 2 = fp32 C[m][DM]
// ---------------------------------------------------------------------------
template<int ABF16, int OMODE>
__global__ __launch_bounds__(256)
void gemm128(const void* __restrict__ Ap, const u16* __restrict__ Wt,
             const float* __restrict__ bias, void* __restrict__ Cp)
{
  __shared__ __align__(16) u16 Asm[128][40];   // [m][k] rows padded to 80B
  __shared__ __align__(16) u16 Bsm[128][40];   // [n][k]
  const int bm = blockIdx.y * 128, bn = blockIdx.x * 128;
  const int t = threadIdx.x;
  const int wid = t >> 6, l = t & 63, r16 = l & 15, q = l >> 4;
  const int wm = (wid & 1) * 64, wn = (wid >> 1) * 64;
  const int srow = t >> 1, shalf = t & 1;
  floatx4 acc[4][4] = {};

  for (int kc = 0; kc < DM; kc += 32){
    if (ABF16){
      const u16* a = (const u16*)Ap + (size_t)(bm+srow)*DM + kc + shalf*16;
      uint4* dst = (uint4*)&Asm[srow][shalf*16];
      dst[0] = ((const uint4*)a)[0];
      dst[1] = ((const uint4*)a)[1];
    } else {
      const float* a = (const float*)Ap + (size_t)(bm+srow)*DM + kc + shalf*16;
      const float4* a4 = (const float4*)a;
      float4 f0 = a4[0], f1 = a4[1], f2 = a4[2], f3 = a4[3];
      uint4* dst = (uint4*)&Asm[srow][shalf*16];
      dst[0] = make_uint4(pack2(f0.x,f0.y), pack2(f0.z,f0.w),
                          pack2(f1.x,f1.y), pack2(f1.z,f1.w));
      dst[1] = make_uint4(pack2(f2.x,f2.y), pack2(f2.z,f2.w),
                          pack2(f3.x,f3.y), pack2(f3.z,f3.w));
    }
    {
      const u16* wsrc = Wt + (size_t)(bn+srow)*DM + kc + shalf*16;
      uint4* dst = (uint4*)&Bsm[srow][shalf*16];
      dst[0] = ((const uint4*)wsrc)[0];
      dst[1] = ((const uint4*)wsrc)[1];
    }
    __syncthreads();
    bhalf8 af[4], bf[4];
    #pragma unroll
    for (int i = 0; i < 4; ++i) af[i] = *(const bhalf8*)&Asm[wm + i*16 + r16][q*8];
    #pragma unroll
    for (int j = 0; j < 4; ++j) bf[j] = *(const bhalf8*)&Bsm[wn + j*16 + r16][q*8];
    #pragma unroll
    for (int i = 0; i < 4; ++i)
      #pragma unroll
      for (int j = 0; j < 4; ++j)
        acc[i][j] = MFMA16(af[i], bf[j], acc[i][j]);
    __syncthreads();
  }

  // epilogue: D row = 16i + 4q + r, col = 16j + r16 (within wave's 64x64)
  #pragma unroll
  for (int j = 0; j < 4; ++j){
    const int n = bn + wn + j*16 + r16;
    const float bj = bias[n];
    #pragma unroll
    for (int i = 0; i < 4; ++i){
      const int m0 = bm + wm + i*16 + q*4;
      if (OMODE == 0){
        u16* C = (u16*)Cp;
        #pragma unroll
        for (int r = 0; r < 4; ++r)
          C[(size_t)(m0+r)*DM + n] = f2b(acc[i][j][r] + bj);
      } else if (OMODE == 1){
        u16* C = (u16*)Cp;
        const int b = m0 >> 11, s = m0 & 2047;
        const int h = n >> 6,  d = n & 63;
        u32 v0 = pack2(acc[i][j][0] + bj, acc[i][j][1] + bj);
        u32 v1 = pack2(acc[i][j][2] + bj, acc[i][j][3] + bj);
        *(uint2*)&C[(size_t)((b*NH + h)*DK + d)*SEQ + s] = make_uint2(v0, v1);
      } else {
        float* C = (float*)Cp;
        #pragma unroll
        for (int r = 0; r < 4; ++r)
          C[(size_t)(m0+r)*DM + n] = acc[i][j][r] + bj;
      }
    }
  }
}

// ---------------------------------------------------------------------------
// Stats: softmax over i (query axis). For each (b,h,j): m_j, l_j.
// Block = (64-wide j tile, bh). S via MFMA; reduce over i with shfl + online merge.
// ---------------------------------------------------------------------------
__global__ __launch_bounds__(256)
void attn_stats(const u16* __restrict__ Qb, const u16* __restrict__ Kb,
                float* __restrict__ Mj, float* __restrict__ Lj)
{
  __shared__ __align__(16) u16 Kls[64][72], Qls[64][72];
  __shared__ float pm[4][64], pl[4][64];
  const int j0 = blockIdx.x * 64, bh = blockIdx.y;
  const int b = bh >> 4, h = bh & 15;
  const int t = threadIdx.x, wid = t >> 6, l = t & 63, r16 = l & 15, q = l >> 4;
  const int sr = t >> 2, sc = t & 3;
  {
    const u16* src = Kb + (size_t)(b*SEQ + j0 + sr)*DM + h*DK;
    *(uint4*)&Kls[sr][sc*8]      = *(const uint4*)(src + sc*8);
    *(uint4*)&Kls[sr][sc*8 + 32] = *(const uint4*)(src + sc*8 + 32);
  }
  __syncthreads();
  bhalf8 kf[2][4];
  #pragma unroll
  for (int ch = 0; ch < 2; ++ch)
    #pragma unroll
    for (int st = 0; st < 4; ++st)
      kf[ch][st] = *(const bhalf8*)&Kls[st*16 + r16][ch*32 + q*8];

  float rm[4] = {-1e30f,-1e30f,-1e30f,-1e30f}, rl[4] = {0.f,0.f,0.f,0.f};

  for (int it = 0; it < SEQ/64; ++it){
    __syncthreads();
    {
      const u16* src = Qb + (size_t)(b*SEQ + it*64 + sr)*DM + h*DK;
      *(uint4*)&Qls[sr][sc*8]      = *(const uint4*)(src + sc*8);
      *(uint4*)&Qls[sr][sc*8 + 32] = *(const uint4*)(src + sc*8 + 32);
    }
    __syncthreads();
    bhalf8 qf0 = *(const bhalf8*)&Qls[wid*16 + r16][q*8];
    bhalf8 qf1 = *(const bhalf8*)&Qls[wid*16 + r16][32 + q*8];
    #pragma unroll
    for (int st = 0; st < 4; ++st){
      floatx4 acc = {};
      acc = MFMA16(qf0, kf[0][st], acc);
      acc = MFMA16(qf1, kf[1][st], acc);
      float s0 = acc[0]*0.125f, s1 = acc[1]*0.125f;
      float s2 = acc[2]*0.125f, s3 = acc[3]*0.125f;
      float tm = fmaxf(fmaxf(s0,s1), fmaxf(s2,s3));
      tm = fmaxf(tm, __shfl_xor(tm, 16));
      tm = fmaxf(tm, __shfl_xor(tm, 32));
      float te = __expf(s0-tm) + __expf(s1-tm) + __expf(s2-tm) + __expf(s3-tm);
      te += __shfl_xor(te, 16);
      te += __shfl_xor(te, 32);
      float mn = fmaxf(rm[st], tm);
      rl[st] = rl[st]*__expf(rm[st]-mn) + te*__expf(tm-mn);
      rm[st] = mn;
    }
  }
  if (q == 0){
    #pragma unroll
    for (int st = 0; st < 4; ++st){
      pm[wid][st*16 + r16] = rm[st];
      pl[wid][st*16 + r16] = rl[st];
    }
  }
  __syncthreads();
  if (t < 64){
    float m4 = fmaxf(fmaxf(pm[0][t], pm[1][t]), fmaxf(pm[2][t], pm[3][t]));
    float l4 = pl[0][t]*__expf(pm[0][t]-m4) + pl[1][t]*__expf(pm[1][t]-m4)
             + pl[2][t]*__expf(pm[2][t]-m4) + pl[3][t]*__expf(pm[3][t]-m4);
    Mj[(size_t)bh*SEQ + j0 + t] = m4;
    Lj[(size_t)bh*SEQ + j0 + t] = l4;
  }
}

// ---------------------------------------------------------------------------
// PV: X[i][d] = sum_j exp(s_ij - m_j)/l_j * V[j][d].
// Block = (64-wide i tile, bh); scans j tiles. S via MFMA (C-layout), P -> LDS
// (A-layout), PV via MFMA with Vt ([d][s] rows -> contiguous B-frags).
// ---------------------------------------------------------------------------
__global__ __launch_bounds__(256)
void attn_pv(const u16* __restrict__ Qb, const u16* __restrict__ Kb,
             const u16* __restrict__ Vt, const float* __restrict__ Mj,
             const float* __restrict__ Lj, u16* __restrict__ Xb)
{
  __shared__ __align__(16) u16 Qls[64][72], Kls[64][72], Vls[64][72], Pls[64][72];
  __shared__ float mlm[64], mll[64];
  const int i0 = blockIdx.x * 64, bh = blockIdx.y;
  const int b = bh >> 4, h = bh & 15;
  const int t = threadIdx.x, wid = t >> 6, l = t & 63, r16 = l & 15, q = l >> 4;
  const int sr = t >> 2, sc = t & 3;
  {
    const u16* src = Qb + (size_t)(b*SEQ + i0 + sr)*DM + h*DK;
    *(uint4*)&Qls[sr][sc*8]      = *(const uint4*)(src + sc*8);
    *(uint4*)&Qls[sr][sc*8 + 32] = *(const uint4*)(src + sc*8 + 32);
  }
  __syncthreads();
  bhalf8 qf0 = *(const bhalf8*)&Qls[wid*16 + r16][q*8];
  bhalf8 qf1 = *(const bhalf8*)&Qls[wid*16 + r16][32 + q*8];
  floatx4 xacc[4] = {};

  for (int jt = 0; jt < SEQ/64; ++jt){
    const int j0 = jt*64;
    __syncthreads();
    {
      const u16* ks = Kb + (size_t)(b*SEQ + j0 + sr)*DM + h*DK;
      *(uint4*)&Kls[sr][sc*8]      = *(const uint4*)(ks + sc*8);
      *(uint4*)&Kls[sr][sc*8 + 32] = *(const uint4*)(ks + sc*8 + 32);
      const u16* vs = Vt + (size_t)((b*NH + h)*DK + sr)*SEQ + j0;
      *(uint4*)&Vls[sr][sc*8]      = *(const uint4*)(vs + sc*8);
      *(uint4*)&Vls[sr][sc*8 + 32] = *(const uint4*)(vs + sc*8 + 32);
    }
    if (t < 64){
      mlm[t] = Mj[(size_t)bh*SEQ + j0 + t];
      mll[t] = 1.f / fmaxf(Lj[(size_t)bh*SEQ + j0 + t], 1e-30f);
    }
    __syncthreads();
    // S = Q K^T for this wave's 16-row strip; apply softmax column stats.
    #pragma unroll
    for (int st = 0; st < 4; ++st){
      bhalf8 k0f = *(const bhalf8*)&Kls[st*16 + r16][q*8];
      bhalf8 k1f = *(const bhalf8*)&Kls[st*16 + r16][32 + q*8];
      floatx4 acc = {};
      acc = MFMA16(qf0, k0f, acc);
      acc = MFMA16(qf1, k1f, acc);
      const int col = st*16 + r16;
      const float mj = mlm[col], li = mll[col];
      #pragma unroll
      for (int r = 0; r < 4; ++r)
        Pls[wid*16 + q*4 + r][col] = f2b(__expf(acc[r]*0.125f - mj) * li);
    }
    __syncthreads();   // publish P (cross-lane within wave + keep iters aligned)
    bhalf8 pf0 = *(const bhalf8*)&Pls[wid*16 + r16][q*8];
    bhalf8 pf1 = *(const bhalf8*)&Pls[wid*16 + r16][32 + q*8];
    #pragma unroll
    for (int dst = 0; dst < 4; ++dst){
      bhalf8 v0f = *(const bhalf8*)&Vls[dst*16 + r16][q*8];
      bhalf8 v1f = *(const bhalf8*)&Vls[dst*16 + r16][32 + q*8];
      xacc[dst] = MFMA16(pf0, v0f, xacc[dst]);
      xacc[dst] = MFMA16(pf1, v1f, xacc[dst]);
    }
  }
  #pragma unroll
  for (int dst = 0; dst < 4; ++dst)
    #pragma unroll
    for (int r = 0; r < 4; ++r)
      Xb[(size_t)(b*SEQ + i0 + wid*16 + q*4 + r)*DM + h*DK + dst*16 + r16]
        = f2b(xacc[dst][r]);
}

// ---------------------------------------------------------------------------
extern "C" void kernel_launch(void* const* d_in, const int* in_sizes, int n_in,
                              void* d_out, int out_size, void* d_ws, size_t ws_size,
                              hipStream_t stream)
{
  const float* q  = (const float*)d_in[0];
  const float* k  = (const float*)d_in[1];
  const float* v  = (const float*)d_in[2];
  const float* Wq = (const float*)d_in[3];
  const float* bq = (const float*)d_in[4];
  const float* Wk = (const float*)d_in[5];
  const float* bk = (const float*)d_in[6];
  const float* Wv = (const float*)d_in[7];
  const float* bv = (const float*)d_in[8];
  const float* Wo = (const float*)d_in[9];
  const float* bo = (const float*)d_in[10];
  float* out = (float*)d_out;

  // ws: [Mj 256K][Lj 256K][Wtq|Wtk|Wtv|Wto 2MB each][Qb 8M][Kb 8M][Vt 8M][Xb 8M]
  char* ws = (char*)d_ws;
  const size_t STATB = (size_t)32 * SEQ * sizeof(float);   // 256 KiB
  const size_t WTB   = (size_t)DM * DM * sizeof(u16);      // 2 MiB
  const size_t TOKB  = (size_t)NTOK * DM * sizeof(u16);    // 8 MiB
  float* Mj  = (float*)(ws);
  float* Lj  = (float*)(ws + STATB);
  u16*   Wtq = (u16*)(ws + 2*STATB);
  u16*   Wtk = (u16*)(ws + 2*STATB + WTB);
  u16*   Wtv = (u16*)(ws + 2*STATB + 2*WTB);
  u16*   Wto = (u16*)(ws + 2*STATB + 3*WTB);
  u16*   Qb  = (u16*)(ws + 2*STATB + 4*WTB);
  u16*   Kb  = (u16*)(ws + 2*STATB + 4*WTB + TOKB);
  u16*   Vt  = (u16*)(ws + 2*STATB + 4*WTB + 2*TOKB);
  u16*   Xb  = (u16*)(ws + 2*STATB + 4*WTB + 3*TOKB);

  dim3 blk(256);
  dim3 gt(16, 16);
  wtrans<<<gt, blk, 0, stream>>>(Wq, Wtq);
  wtrans<<<gt, blk, 0, stream>>>(Wk, Wtk);
  wtrans<<<gt, blk, 0, stream>>>(Wv, Wtv);
  wtrans<<<gt, blk, 0, stream>>>(Wo, Wto);

  dim3 gg(DM/128, NTOK/128);   // (8, 32)
  gemm128<0,0><<<gg, blk, 0, stream>>>(q, Wtq, bq, Qb);
  gemm128<0,0><<<gg, blk, 0, stream>>>(k, Wtk, bk, Kb);
  gemm128<0,1><<<gg, blk, 0, stream>>>(v, Wtv, bv, Vt);

  dim3 ga(SEQ/64, 32);         // (32, 32)
  attn_stats<<<ga, blk, 0, stream>>>(Qb, Kb, Mj, Lj);
  attn_pv<<<ga, blk, 0, stream>>>(Qb, Kb, Vt, Mj, Lj, Xb);

  gemm128<1,2><<<gg, blk, 0, stream>>>(Xb, Wto, bo, out);
}